// Round 6
// baseline (650.453 us; speedup 1.0000x reference)
//
#include <hip/hip_runtime.h>
#include <hip/hip_fp16.h>
#include <stdint.h>

// Problem constants (B, S, H from the reference)
#define B_SZ 32
#define S_SZ 2048
#define H_SZ 1024
#define M_SZ (B_SZ * S_SZ)   // 65536 rows of the big GEMM

typedef _Float16 half8 __attribute__((ext_vector_type(8)));
typedef float floatx4 __attribute__((ext_vector_type(4)));

struct h4 { _Float16 x, y, z, w; };   // 8-byte packed fp16x4

// ---------------- fp32 -> fp16 convert (Wk only) ----------------
__global__ __launch_bounds__(256) void convert_f32_to_f16(
    const float* __restrict__ in, h4* __restrict__ out, int n4) {
  int i = blockIdx.x * blockDim.x + threadIdx.x;
  int stride = gridDim.x * blockDim.x;
  const float4* in4 = (const float4*)in;
  for (; i < n4; i += stride) {
    float4 f = in4[i];
    h4 o;
    o.x = (_Float16)f.x; o.y = (_Float16)f.y;
    o.z = (_Float16)f.z; o.w = (_Float16)f.w;
    out[i] = o;
  }
}

// ---------------- query = hidden @ Wq^T  (fp32 exact, tiny) ----------------
__global__ __launch_bounds__(256) void query_kernel(
    const float* __restrict__ hidden, const float* __restrict__ Wq,
    float* __restrict__ q) {
  int t = blockIdx.x * blockDim.x + threadIdx.x;   // 32768 threads
  int b = t & 31;
  int n = t >> 5;
  const float4* h4p = (const float4*)(hidden + (size_t)b * H_SZ);
  const float4* w4p = (const float4*)(Wq + (size_t)n * H_SZ);
  float acc = 0.f;
  #pragma unroll 4
  for (int i = 0; i < H_SZ / 4; ++i) {
    float4 h = h4p[i], w = w4p[i];
    acc = fmaf(h.x, w.x, acc);
    acc = fmaf(h.y, w.y, acc);
    acc = fmaf(h.z, w.z, acc);
    acc = fmaf(h.w, w.w, acc);
  }
  q[(size_t)b * H_SZ + n] = acc;
}

// ---------------- async global->LDS, 16B per lane (per-lane SOURCE address) ----------------
__device__ __forceinline__ void gl_lds16(const void* g, void* l) {
  __builtin_amdgcn_global_load_lds(
      (const __attribute__((address_space(1))) void*)g,
      (__attribute__((address_space(3))) void*)l,
      16, 0, 0);
}

__device__ __forceinline__ float fast_tanh(float x) {
  float ax = fabsf(x);
  float e = __expf(ax * -2.0f);
  float t = (1.0f - e) / (1.0f + e);
  return copysignf(t, x);
}

// ---------------- fused fp32->fp16 + keys-GEMM + tanh + v-dot ----------------
// C[m,n] = sum_k A[m,k] * Bt[n,k]
// partial[bn][m] = sum_{n in col-tile} v[n]*tanh(q[b,n]+C[m,n])
//
// Round-6 structure (A direct-from-L2 fragments + depth-2 counted B pipeline):
//  - NO A LDS staging: lane L of m-tile m loads its MFMA fragment
//    A[R0+w*32+m*16+(L&15)][k0+8*quad..+8] straight from global (L2-hot via
//    the XCD swizzle: 8 bn-blocks share the row panel), cvt fp32->fp16 in
//    regs (same RTE numerics).  Removes A's gl_lds/ds_write/ds_read and the
//    As buffers; LDS pipe load drops ~40%.
//  - B: global_load_lds into a TRIPLE-buffered Bs (DMA 2 tiles ahead).
//    No vmcnt drain in the loop: cvtA(t)'s register dep on arf(t) (issued
//    AFTER stageB(t+1) last iter) makes the compiler emit a counted vmcnt
//    that drains B(t+1) while B(t+2) stays in flight; lgkmcnt(0)+s_barrier
//    then publishes tile t+1 chip-wide.  A-frag loads for t+1 are issued
//    right after cvtA(t) frees the arf regs (1-deep register prefetch).
//  - LDS = 3x8KB Bs + 1KB q/v = 25.6 KB; __launch_bounds__(256,4) ->
//    4 blocks/CU (16 waves), VGPR-bounded (acc 64 AGPR + ~64 arch).
//  - Full unroll keeps %3/%2 indices compile-time (rule #20).
#define TILE 128
#define BK 32
#define NT (H_SZ / BK)   // 32 K-tiles

__global__ __launch_bounds__(256, 4) void fused_keys_kernel(
    const float* __restrict__ A,       // enc fp32, M_SZ x H_SZ
    const _Float16* __restrict__ Bt,   // Wk fp16, H_SZ x H_SZ
    const float* __restrict__ q,       // B_SZ x H_SZ (fp32)
    const float* __restrict__ v,       // H_SZ
    float* __restrict__ partial)       // 8 x M_SZ
{
  __shared__ __align__(16) _Float16 Bs[3][TILE * BK];   // 3 x 8 KB fp16
  __shared__ float q_l[TILE];
  __shared__ float v_l[TILE];

  const int tid  = threadIdx.x;
  const int w    = tid >> 6;       // wave 0..3
  const int lane = tid & 63;

  // XCD-aware bijective swizzle: the 8 bn-blocks sharing one A row-tile all
  // land on the same XCD. nwg = 4096, 4096 % 8 == 0 -> bijective.
  const int hw   = blockIdx.x;
  const int xcd  = hw & 7;
  const int slot = hw >> 3;
  const int bn   = slot & 7;
  const int bm   = ((slot >> 3) << 3) | xcd;   // bm & 7 == xcd

  const int R0   = bm * TILE;         // global row base (b*S + s)
  const int C0   = bn * TILE;         // global col base (n dim of H)
  const int bidx = R0 >> 11;          // batch index; uniform (2048 % 128 == 0)

  if (tid < TILE) {
    q_l[tid] = q[(size_t)bidx * H_SZ + C0 + tid];
    v_l[tid] = v[C0 + tid];
  }

  const int cL   = lane & 15, quad = lane >> 4;
  const int sB   = (cL >> 1) & 3;  // B read swizzle key (matches write involution)

  floatx4 acc[2][8];
  #pragma unroll
  for (int m = 0; m < 2; ++m)
    #pragma unroll
    for (int n = 0; n < 8; ++n)
      acc[m][n] = (floatx4){0.f, 0.f, 0.f, 0.f};

  // ---- A fragment source pointers (per-lane, direct from global/L2) ----
  // m-tile m: row = R0 + w*32 + m*16 + cL ; k elems 8*quad .. 8*quad+7
  const float* Af0 = A + (size_t)(R0 + w * 32 +  0 + cL) * H_SZ + 8 * quad;
  const float* Af1 = A + (size_t)(R0 + w * 32 + 16 + cL) * H_SZ + 8 * quad;

  float4 arf[4];   // fragment fp32 staging: [m*2+h] = floats 8q+4h .. +4

  auto loadAfrag = [&](int kt2) {
    const float4* p0 = (const float4*)(Af0 + kt2 * BK);
    const float4* p1 = (const float4*)(Af1 + kt2 * BK);
    arf[0] = p0[0]; arf[1] = p0[1];
    arf[2] = p1[0]; arf[3] = p1[1];
  };

  // ---- B staging lane decomposition (global_load_lds, source-swizzled) ----
  const int brow_l = lane >> 2;   // 4 lanes cover one 64B fp16 row
  const int bp     = lane & 3;    // physical 16B chunk 0..3
  const _Float16* Bblk = Bt + (size_t)C0 * H_SZ;

  auto stageB = [&](int kt2, int b) {
    const int kof = kt2 * BK;
    #pragma unroll
    for (int j = 0; j < 2; ++j) {
      const int row = w * 32 + j * 16 + brow_l;
      const int cg  = bp ^ ((row >> 1) & 3);
      gl_lds16(Bblk + (size_t)row * H_SZ + kof + cg * 8,
               (char*)&Bs[b][0] + (w * 128 + j * 64) * 16);
    }
  };

  // ---- prologue: B tiles 0,1 in flight; A frag 0 in flight; full drain once ----
  stageB(0, 0);
  stageB(1, 1);
  loadAfrag(0);
  __syncthreads();                 // one-time vmcnt(0)+lgkm(0)+barrier: tile 0 ready

  // ---- main loop: compute(t) from Bs[t%3] while B(t+2) DMA + A(t+1) fly ----
  #pragma unroll
  for (int t = 0; t < NT; ++t) {
    if (t + 2 < NT)
      stageB(t + 2, (t + 2) % 3);

    // cvt arf(t) -> af: compiler emits counted vmcnt here (arf(t) was issued
    // AFTER stageB(t+1) last iter => B(t+1) drained; B(t+2) stays in flight)
    half8 af0 = (half8){(_Float16)arf[0].x, (_Float16)arf[0].y, (_Float16)arf[0].z, (_Float16)arf[0].w,
                        (_Float16)arf[1].x, (_Float16)arf[1].y, (_Float16)arf[1].z, (_Float16)arf[1].w};
    half8 af1 = (half8){(_Float16)arf[2].x, (_Float16)arf[2].y, (_Float16)arf[2].z, (_Float16)arf[2].w,
                        (_Float16)arf[3].x, (_Float16)arf[3].y, (_Float16)arf[3].z, (_Float16)arf[3].w};

    if (t + 1 < NT)
      loadAfrag(t + 1);            // regs free after cvt; 1-deep prefetch

    // B fragments in 2 groups of 4 (caps register pressure)
    const int bb = t % 3;
    #pragma unroll
    for (int g = 0; g < 2; ++g) {
      half8 bf[4];
      #pragma unroll
      for (int n = 0; n < 4; ++n) {
        const int r = (g * 4 + n) * 16 + cL;
        bf[n] = *(const half8*)(&Bs[bb][r * BK] + ((quad ^ sB) << 3));
      }
      __builtin_amdgcn_s_setprio(1);
      #pragma unroll
      for (int n = 0; n < 4; ++n) {
        acc[0][g * 4 + n] = __builtin_amdgcn_mfma_f32_16x16x32_f16(af0, bf[n], acc[0][g * 4 + n], 0, 0, 0);
        acc[1][g * 4 + n] = __builtin_amdgcn_mfma_f32_16x16x32_f16(af1, bf[n], acc[1][g * 4 + n], 0, 0, 0);
      }
      __builtin_amdgcn_s_setprio(0);
    }

    if (t + 1 < NT) {
      asm volatile("s_waitcnt lgkmcnt(0)" ::: "memory");
      __builtin_amdgcn_s_barrier();   // publishes tile t+1 (own DMA drained above)
    }
  }

  // ---- epilogue: v[n]*tanh(q+c), each wave owns its 32 rows ----
  float qv[8], vv[8];
  #pragma unroll
  for (int n = 0; n < 8; ++n) {
    const int col = n * 16 + cL;
    qv[n] = q_l[col];
    vv[n] = v_l[col];
  }
  // C/D layout: col = lane&15, row = quad*4 + reg  [m89-verified]
  #pragma unroll
  for (int m = 0; m < 2; ++m) {
    #pragma unroll
    for (int r = 0; r < 4; ++r) {
      float s = 0.f;
      #pragma unroll
      for (int n = 0; n < 8; ++n)
        s += vv[n] * fast_tanh(qv[n] + acc[m][n][r]);
      // reduce across the 16 lanes (cL) sharing this row
      s += __shfl_xor(s, 1);
      s += __shfl_xor(s, 2);
      s += __shfl_xor(s, 4);
      s += __shfl_xor(s, 8);
      if (cL == 0)
        partial[(size_t)bn * M_SZ + R0 + w * 32 + m * 16 + quad * 4 + r] = s;
    }
  }
}

// ---------------- masked softmax over S per batch row ----------------
__global__ __launch_bounds__(256) void softmax_kernel(
    const float* __restrict__ partial, const int* __restrict__ lengths,
    float* __restrict__ out) {
  __shared__ float wred[4];
  __shared__ float wsum[4];
  const int b = blockIdx.x;
  const int tid = threadIdx.x;
  const int len = lengths[b];

  float lg[8];
  #pragma unroll
  for (int i = 0; i < 8; ++i) {
    const int s = tid + i * 256;
    const size_t row = (size_t)b * S_SZ + s;
    float l = 0.f;
    #pragma unroll
    for (int nt = 0; nt < 8; ++nt) l += partial[(size_t)nt * M_SZ + row];
    lg[i] = (s < len) ? l : -INFINITY;
  }

  float mx = lg[0];
  #pragma unroll
  for (int i = 1; i < 8; ++i) mx = fmaxf(mx, lg[i]);
  #pragma unroll
  for (int off = 32; off; off >>= 1) mx = fmaxf(mx, __shfl_xor(mx, off));
  if ((tid & 63) == 0) wred[tid >> 6] = mx;
  __syncthreads();
  mx = fmaxf(fmaxf(wred[0], wred[1]), fmaxf(wred[2], wred[3]));

  float pe[8];
  float sum = 0.f;
  #pragma unroll
  for (int i = 0; i < 8; ++i) {
    float e = (lg[i] == -INFINITY) ? 0.f : __expf(lg[i] - mx);
    pe[i] = e;
    sum += e;
  }
  #pragma unroll
  for (int off = 32; off; off >>= 1) sum += __shfl_xor(sum, off);
  if ((tid & 63) == 0) wsum[tid >> 6] = sum;
  __syncthreads();
  sum = wsum[0] + wsum[1] + wsum[2] + wsum[3];
  const float inv = 1.0f / sum;

  #pragma unroll
  for (int i = 0; i < 8; ++i) {
    const int s = tid + i * 256;
    out[(size_t)b * S_SZ + s] = pe[i] * inv;
  }
}

extern "C" void kernel_launch(void* const* d_in, const int* in_sizes, int n_in,
                              void* d_out, int out_size, void* d_ws, size_t ws_size,
                              hipStream_t stream) {
  const float* hidden  = (const float*)d_in[0];  // (32, 1024)
  const float* enc     = (const float*)d_in[1];  // (32, 2048, 1024)
  const int*   lengths = (const int*)d_in[2];    // (32,)
  const float* Wq      = (const float*)d_in[3];  // (1024, 1024)
  const float* Wk      = (const float*)d_in[4];  // (1024, 1024)
  const float* v       = (const float*)d_in[5];  // (1024,)
  float* out = (float*)d_out;                    // (32, 2048) fp32

  // ws layout: B16 (2 MB) | q (128 KB) | partial (2 MB)   — 4.2 MB total
  char* ws = (char*)d_ws;
  _Float16* B16     = (_Float16*)ws;
  float*    q       = (float*)(ws + 2097152);
  float*    partial = (float*)(ws + 2097152 + 131072);

  convert_f32_to_f16<<<1024, 256, 0, stream>>>(Wk, (h4*)B16, (H_SZ * H_SZ) / 4);
  query_kernel<<<128, 256, 0, stream>>>(hidden, Wq, q);
  fused_keys_kernel<<<(M_SZ / TILE) * (H_SZ / TILE), 256, 0, stream>>>(enc, B16, q, v, partial);
  softmax_kernel<<<B_SZ, 256, 0, stream>>>(partial, lengths, out);
}

// Round 7
// 591.214 us; speedup vs baseline: 1.1002x; 1.1002x over previous
//
#include <hip/hip_runtime.h>
#include <hip/hip_fp16.h>
#include <stdint.h>

// Problem constants (B, S, H from the reference)
#define B_SZ 32
#define S_SZ 2048
#define H_SZ 1024
#define M_SZ (B_SZ * S_SZ)   // 65536 rows of the big GEMM

typedef _Float16 half8 __attribute__((ext_vector_type(8)));
typedef float floatx4 __attribute__((ext_vector_type(4)));

struct h4 { _Float16 x, y, z, w; };   // 8-byte packed fp16x4

// ---------------- fp32 -> fp16 convert (Wk only) ----------------
__global__ __launch_bounds__(256) void convert_f32_to_f16(
    const float* __restrict__ in, h4* __restrict__ out, int n4) {
  int i = blockIdx.x * blockDim.x + threadIdx.x;
  int stride = gridDim.x * blockDim.x;
  const float4* in4 = (const float4*)in;
  for (; i < n4; i += stride) {
    float4 f = in4[i];
    h4 o;
    o.x = (_Float16)f.x; o.y = (_Float16)f.y;
    o.z = (_Float16)f.z; o.w = (_Float16)f.w;
    out[i] = o;
  }
}

// ---------------- query = hidden @ Wq^T  (fp32 exact, tiny) ----------------
__global__ __launch_bounds__(256) void query_kernel(
    const float* __restrict__ hidden, const float* __restrict__ Wq,
    float* __restrict__ q) {
  int t = blockIdx.x * blockDim.x + threadIdx.x;   // 32768 threads
  int b = t & 31;
  int n = t >> 5;
  const float4* h4p = (const float4*)(hidden + (size_t)b * H_SZ);
  const float4* w4p = (const float4*)(Wq + (size_t)n * H_SZ);
  float acc = 0.f;
  #pragma unroll 4
  for (int i = 0; i < H_SZ / 4; ++i) {
    float4 h = h4p[i], w = w4p[i];
    acc = fmaf(h.x, w.x, acc);
    acc = fmaf(h.y, w.y, acc);
    acc = fmaf(h.z, w.z, acc);
    acc = fmaf(h.w, w.w, acc);
  }
  q[(size_t)b * H_SZ + n] = acc;
}

// ---------------- async global->LDS, 16B per lane ----------------
// LDS dest must be the WAVE-UNIFORM base; HW adds lane*16.
__device__ __forceinline__ void gl_lds16(const void* g, void* l) {
  __builtin_amdgcn_global_load_lds(
      (const __attribute__((address_space(1))) void*)g,
      (__attribute__((address_space(3))) void*)l,
      16, 0, 0);
}

__device__ __forceinline__ float fast_tanh(float x) {
  float ax = fabsf(x);
  float e = __expf(ax * -2.0f);
  float t = (1.0f - e) / (1.0f + e);
  return copysignf(t, x);
}

// ---------------- fused fp32->fp16 + keys-GEMM + tanh + v-dot ----------------
// Round-7: 256x256 tile, BK=64, 8 waves (2M x 4N), dbuf LDS, 1 barrier/K-tile.
//  - per wave-step 64 MFMA (4x the 128-tile skeleton) per half the staged bytes.
//  - A: fp32 global -> regs -> RTE cvt fp16 -> chunk-XOR-swizzled ds_write.
//  - B: global_load_lds, pre-swizzled per-lane SOURCE (dest linear).
//  - LDS tiles [128][64] fp16 (128B rows, 8x16B chunks); phys chunk =
//    logical ^ ((row>>1)&7) both on write and read (bank-free, 2-way max).
//  - All vmcnt waits are compiler-derived from the cvt register deps; the
//    K-tile-end barrier is lgkmcnt(0)-only (+sched_barrier, rule 18).
//  - T5 setprio around each 32-MFMA cluster.
#define NKT 16   // 1024 / 64

__global__ __launch_bounds__(512, 2) void fused_keys_kernel(
    const float* __restrict__ A,       // enc fp32, M_SZ x H_SZ
    const _Float16* __restrict__ Bt,   // Wk fp16, H_SZ x H_SZ
    const float* __restrict__ q,       // B_SZ x H_SZ (fp32)
    const float* __restrict__ v,       // H_SZ
    float* __restrict__ partial)       // 16 x M_SZ
{
  __shared__ __align__(16) _Float16 As[2][2][128 * 64];   // [buf][mhalf] 64 KB
  __shared__ __align__(16) _Float16 Bs[2][2][128 * 64];   // [buf][nhalf] 64 KB
  __shared__ float q_l[256];
  __shared__ float v_l[256];

  const int tid  = threadIdx.x;
  const int w    = tid >> 6;        // wave 0..7
  const int lane = tid & 63;
  const int wm   = w >> 2;          // 0..1 : M half (rows wm*128..+128)
  const int wn   = w & 3;           // 0..3 : N quarter (cols wn*64..+64)
  const int nh   = wn >> 1;         // B half this wave reads

  // XCD-aware bijective swizzle: nwg=1024; XCD x gets slots x*128..+127,
  // i.e. 32 consecutive bm with all 4 bn -> A panel shared within one L2.
  const int orig = blockIdx.x;
  const int slot = (orig & 7) * 128 + (orig >> 3);
  const int bn   = slot & 3;
  const int bm   = slot >> 2;       // 0..255

  const int R0   = bm * 256;        // global row base (b*S + s)
  const int C0   = bn * 256;        // global col base (n dim of H)
  const int bidx = R0 >> 11;        // batch index (2048 % 256 == 0)

  if (tid < 256) {
    q_l[tid] = q[(size_t)bidx * H_SZ + C0 + tid];
    v_l[tid] = v[C0 + tid];
  }

  const int cL   = lane & 15, quad = lane >> 4;
  const int sKey = (cL >> 1) & 7;   // read swizzle key (row>>1)&7, m*8 drops out

  floatx4 acc[8][4];
  #pragma unroll
  for (int m = 0; m < 8; ++m)
    #pragma unroll
    for (int n = 0; n < 4; ++n)
      acc[m][n] = (floatx4){0.f, 0.f, 0.f, 0.f};

  // ---- A staging decomposition: thread stages 16 floats of row arow ----
  const int arow = tid >> 2;        // 0..127 (row within a 128-row half)
  const int aseg = tid & 3;         // 16-float segment
  const int akey = (arow >> 1) & 7;
  const int apc0 = (2 * aseg) ^ akey;       // phys chunk, floats seg*16..+8
  const int apc1 = (2 * aseg + 1) ^ akey;   // phys chunk, floats seg*16+8..+16
  const float* Asrc0 = A + (size_t)(R0 + arow) * H_SZ + aseg * 16;
  const float* Asrc1 = A + (size_t)(R0 + 128 + arow) * H_SZ + aseg * 16;

  const _Float16* Bblk = Bt + (size_t)C0 * H_SZ;

  float4 ar[4];   // A staging regs (one half in flight at a time)

  // ---- B half-tiles via gl_lds, source chunk pre-swizzled ----
  auto issueB = [&](int kt2, int nb) {
    const int kof = kt2 * 64;
    #pragma unroll
    for (int h = 0; h < 2; ++h)
      #pragma unroll
      for (int j = 0; j < 2; ++j) {
        const int c   = j * 512 + w * 64 + lane;     // 16B-chunk id, 0..1023
        const int row = c >> 3;
        const int cg  = (c & 7) ^ ((row >> 1) & 7);  // pre-swizzled source chunk
        gl_lds16(Bblk + (size_t)(h * 128 + row) * H_SZ + kof + cg * 8,
                 (char*)&Bs[nb][h][0] + (j * 512 + w * 64) * 16);
      }
  };

  auto loadA = [&](int kt2, int half) {
    const float4* p = (const float4*)((half ? Asrc1 : Asrc0) + kt2 * 64);
    ar[0] = p[0]; ar[1] = p[1]; ar[2] = p[2]; ar[3] = p[3];
  };

  auto writeA = [&](int nb, int half) {
    // compiler-derived vmcnt wait on ar here (drains everything issued before)
    half8 h0 = (half8){(_Float16)ar[0].x, (_Float16)ar[0].y, (_Float16)ar[0].z, (_Float16)ar[0].w,
                       (_Float16)ar[1].x, (_Float16)ar[1].y, (_Float16)ar[1].z, (_Float16)ar[1].w};
    half8 h1 = (half8){(_Float16)ar[2].x, (_Float16)ar[2].y, (_Float16)ar[2].z, (_Float16)ar[2].w,
                       (_Float16)ar[3].x, (_Float16)ar[3].y, (_Float16)ar[3].z, (_Float16)ar[3].w};
    _Float16* dst = &As[nb][half][arow * 64];
    *(half8*)(dst + apc0 * 8) = h0;
    *(half8*)(dst + apc1 * 8) = h1;
  };

  // ---- one 32-MFMA cluster: m-tiles m0..m0+3, all n, both k-slices ----
  auto cluster = [&](int buf, int m0, const half8* bf) {
    half8 af[8];
    #pragma unroll
    for (int mm = 0; mm < 4; ++mm)
      #pragma unroll
      for (int ks = 0; ks < 2; ++ks)
        af[mm * 2 + ks] = *(const half8*)(
            &As[buf][wm][((m0 + mm) * 16 + cL) * 64] + (((ks * 4 + quad) ^ sKey) * 8));
    __builtin_amdgcn_s_setprio(1);
    #pragma unroll
    for (int mm = 0; mm < 4; ++mm)
      #pragma unroll
      for (int ks = 0; ks < 2; ++ks)
        #pragma unroll
        for (int n = 0; n < 4; ++n)
          acc[m0 + mm][n] = __builtin_amdgcn_mfma_f32_16x16x32_f16(
              af[mm * 2 + ks], bf[ks * 4 + n], acc[m0 + mm][n], 0, 0, 0);
    __builtin_amdgcn_s_setprio(0);
  };

  // ---- prologue: stage K-tile 0 into buf 0, full drain once ----
  issueB(0, 0);
  loadA(0, 0); writeA(0, 0);
  loadA(0, 1); writeA(0, 1);
  __syncthreads();                 // vmcnt(0)+lgkm(0)+barrier: tile 0 ready

  // ---- main loop: one barrier per K-tile, staging interleaved ----
  for (int kt = 0; kt < NKT; ++kt) {
    const int buf  = kt & 1;
    const bool more = (kt + 1 < NKT);
    if (more) { issueB(kt + 1, buf ^ 1); loadA(kt + 1, 0); }

    half8 bf[8];   // [ks*4+n], live through both clusters
    #pragma unroll
    for (int ks = 0; ks < 2; ++ks)
      #pragma unroll
      for (int n = 0; n < 4; ++n) {
        const int lr = (wn & 1) * 64 + n * 16 + cL;
        bf[ks * 4 + n] = *(const half8*)(
            &Bs[buf][nh][lr * 64] + (((ks * 4 + quad) ^ sKey) * 8));
      }

    cluster(buf, 0, bf);
    if (more) { writeA(buf ^ 1, 0); loadA(kt + 1, 1); }
    cluster(buf, 4, bf);
    if (more) {
      writeA(buf ^ 1, 1);
      asm volatile("s_waitcnt lgkmcnt(0)" ::: "memory");
      __builtin_amdgcn_sched_barrier(0);
      __builtin_amdgcn_s_barrier();   // publishes K-tile kt+1
    }
  }

  // ---- epilogue: v[n]*tanh(q+c) over this wave's 64 cols, 128 rows ----
  float qv[4], vv[4];
  #pragma unroll
  for (int n = 0; n < 4; ++n) {
    const int col = wn * 64 + n * 16 + cL;
    qv[n] = q_l[col];
    vv[n] = v_l[col];
  }
  // C/D layout: col = lane&15, row = quad*4 + reg  [m89-verified]
  #pragma unroll
  for (int m = 0; m < 8; ++m) {
    #pragma unroll
    for (int r = 0; r < 4; ++r) {
      float s = 0.f;
      #pragma unroll
      for (int n = 0; n < 4; ++n)
        s += vv[n] * fast_tanh(qv[n] + acc[m][n][r]);
      s += __shfl_xor(s, 1);
      s += __shfl_xor(s, 2);
      s += __shfl_xor(s, 4);
      s += __shfl_xor(s, 8);
      if (cL == 0)
        partial[(size_t)(bn * 4 + wn) * M_SZ + R0 + wm * 128 + m * 16 + quad * 4 + r] = s;
    }
  }
}

// ---------------- masked softmax over S per batch row ----------------
__global__ __launch_bounds__(256) void softmax_kernel(
    const float* __restrict__ partial, const int* __restrict__ lengths,
    float* __restrict__ out) {
  __shared__ float wred[4];
  __shared__ float wsum[4];
  const int b = blockIdx.x;
  const int tid = threadIdx.x;
  const int len = lengths[b];

  float lg[8];
  #pragma unroll
  for (int i = 0; i < 8; ++i) {
    const int s = tid + i * 256;
    const size_t row = (size_t)b * S_SZ + s;
    float l = 0.f;
    #pragma unroll
    for (int nt = 0; nt < 16; ++nt) l += partial[(size_t)nt * M_SZ + row];
    lg[i] = (s < len) ? l : -INFINITY;
  }

  float mx = lg[0];
  #pragma unroll
  for (int i = 1; i < 8; ++i) mx = fmaxf(mx, lg[i]);
  #pragma unroll
  for (int off = 32; off; off >>= 1) mx = fmaxf(mx, __shfl_xor(mx, off));
  if ((tid & 63) == 0) wred[tid >> 6] = mx;
  __syncthreads();
  mx = fmaxf(fmaxf(wred[0], wred[1]), fmaxf(wred[2], wred[3]));

  float pe[8];
  float sum = 0.f;
  #pragma unroll
  for (int i = 0; i < 8; ++i) {
    float e = (lg[i] == -INFINITY) ? 0.f : __expf(lg[i] - mx);
    pe[i] = e;
    sum += e;
  }
  #pragma unroll
  for (int off = 32; off; off >>= 1) sum += __shfl_xor(sum, off);
  if ((tid & 63) == 0) wsum[tid >> 6] = sum;
  __syncthreads();
  sum = wsum[0] + wsum[1] + wsum[2] + wsum[3];
  const float inv = 1.0f / sum;

  #pragma unroll
  for (int i = 0; i < 8; ++i) {
    const int s = tid + i * 256;
    out[(size_t)b * S_SZ + s] = pe[i] * inv;
  }
}

extern "C" void kernel_launch(void* const* d_in, const int* in_sizes, int n_in,
                              void* d_out, int out_size, void* d_ws, size_t ws_size,
                              hipStream_t stream) {
  const float* hidden  = (const float*)d_in[0];  // (32, 1024)
  const float* enc     = (const float*)d_in[1];  // (32, 2048, 1024)
  const int*   lengths = (const int*)d_in[2];    // (32,)
  const float* Wq      = (const float*)d_in[3];  // (1024, 1024)
  const float* Wk      = (const float*)d_in[4];  // (1024, 1024)
  const float* v       = (const float*)d_in[5];  // (1024,)
  float* out = (float*)d_out;                    // (32, 2048) fp32

  // ws layout: B16 (2 MB) | q (128 KB) | partial 16 x M (4 MB)  — 6.13 MB
  char* ws = (char*)d_ws;
  _Float16* B16     = (_Float16*)ws;
  float*    q       = (float*)(ws + 2097152);
  float*    partial = (float*)(ws + 2097152 + 131072);

  convert_f32_to_f16<<<1024, 256, 0, stream>>>(Wk, (h4*)B16, (H_SZ * H_SZ) / 4);
  query_kernel<<<128, 256, 0, stream>>>(hidden, Wq, q);
  fused_keys_kernel<<<(M_SZ / 256) * (H_SZ / 256), 512, 0, stream>>>(enc, B16, q, v, partial);
  softmax_kernel<<<B_SZ, 256, 0, stream>>>(partial, lengths, out);
}